// Round 5
// baseline (42.204 us; speedup 1.0000x reference)
//
#include <hip/hip_runtime.h>
#include <hip/hip_bf16.h>

typedef float f32x4 __attribute__((ext_vector_type(4)));
typedef float f32x2 __attribute__((ext_vector_type(2)));
typedef int   i32x2 __attribute__((ext_vector_type(2)));

// out[i] = verified_id[i*ndt + accept_lens[i] - 1], i in [0, BS)
//
// ndt==8 fast path: every byte of vid is needed (one element per 32-B row),
// so read FULL rows with coalesced dwordx4 loads and select the wanted
// element in-register (cndmask tree). All streams are single-use ->
// nontemporal loads/stores to bypass L2 allocation (128 MiB vid would
// otherwise churn the 4 MiB/XCD L2s).
__device__ __forceinline__ float sel8(f32x4 a, f32x4 b, int i) {
    // i in [0,7]: element i of the concatenated row {a,b}. Pure ?: so the
    // compiler emits v_cndmask chains (no scratch, no branches).
    float x0 = (i & 1) ? a.y : a.x;
    float x1 = (i & 1) ? a.w : a.z;
    float x2 = (i & 1) ? b.y : b.x;
    float x3 = (i & 1) ? b.w : b.z;
    float y0 = (i & 2) ? x1 : x0;
    float y1 = (i & 2) ? x3 : x2;
    return (i & 4) ? y1 : y0;
}

__global__ void Model_28681791602777_kernel(const float* __restrict__ vid,
                                            const int* __restrict__ lens,
                                            const int* __restrict__ ndt_ptr,
                                            float* __restrict__ out,
                                            int bs) {
    const int ndt = ndt_ptr[0];           // scalar broadcast (1-elem input)
    const int stride = gridDim.x * blockDim.x;
    int t = blockIdx.x * blockDim.x + threadIdx.x;

    if (ndt == 8) {                       // wave-uniform branch
        const int n2 = bs >> 1;           // pairs of rows
        const f32x4* vid4 = reinterpret_cast<const f32x4*>(vid);
        const i32x2* lens2 = reinterpret_cast<const i32x2*>(lens);
        f32x2* out2 = reinterpret_cast<f32x2*>(out);

        for (; t < n2; t += stride) {
            i32x2 l = __builtin_nontemporal_load(&lens2[t]);
            const int vb = t << 2;        // 4 float4s per row pair
            f32x4 a0 = __builtin_nontemporal_load(&vid4[vb + 0]); // row 2t   lo
            f32x4 b0 = __builtin_nontemporal_load(&vid4[vb + 1]); // row 2t   hi
            f32x4 a1 = __builtin_nontemporal_load(&vid4[vb + 2]); // row 2t+1 lo
            f32x4 b1 = __builtin_nontemporal_load(&vid4[vb + 3]); // row 2t+1 hi
            f32x2 o;
            o.x = sel8(a0, b0, l.x - 1);
            o.y = sel8(a1, b1, l.y - 1);
            __builtin_nontemporal_store(o, &out2[t]);
        }
        // tail (bs odd) — first thread only
        if (blockIdx.x == 0 && threadIdx.x == 0) {
            for (int r = n2 << 1; r < bs; ++r)
                out[r] = vid[r * 8 + lens[r] - 1];
        }
    } else {
        // generic fallback: plain gather
        for (; t < bs; t += stride)
            out[t] = vid[t * ndt + lens[t] - 1];
    }
}

extern "C" void kernel_launch(void* const* d_in, const int* in_sizes, int n_in,
                              void* d_out, int out_size, void* d_ws, size_t ws_size,
                              hipStream_t stream) {
    const float* vid = (const float*)d_in[0];   // verified_id, BS*NDT f32
    const int* lens  = (const int*)d_in[1];     // accept_lens, BS i32
    const int* ndt   = (const int*)d_in[2];     // num_draft_tokens, 1 i32
    float* out = (float*)d_out;                 // BS f32

    const int bs = in_sizes[1];
    const int n2 = bs >> 1;

    const int block = 256;
    int grid = (n2 + block - 1) / block;
    if (grid > 8192) grid = 8192;               // grid-stride the rest
    if (grid < 1) grid = 1;

    Model_28681791602777_kernel<<<grid, block, 0, stream>>>(vid, lens, ndt, out, bs);
}

// Round 6
// 29.760 us; speedup vs baseline: 1.4182x; 1.4182x over previous
//
#include <hip/hip_runtime.h>
#include <hip/hip_bf16.h>

typedef float f32x4 __attribute__((ext_vector_type(4)));
typedef float f32x2 __attribute__((ext_vector_type(2)));
typedef int   i32x2 __attribute__((ext_vector_type(2)));

// out[i] = verified_id[i*ndt + accept_lens[i] - 1], i in [0, BS)
//
// ndt==8 fast path: every byte of vid is needed (one element per 32-B row),
// so read FULL rows with coalesced dwordx4 loads and select the wanted
// element in-register (cndmask tree). Plain (cached) loads: nt-loads
// regressed 29.8->42.2 us (R5) because each 128-B line is consumed by 2
// lanes across 4 separate load instructions -- L2 allocation is what makes
// that pattern single-fetch from HBM.
__device__ __forceinline__ float sel8(f32x4 a, f32x4 b, int i) {
    // i in [0,7]: element i of the concatenated row {a,b}. Pure ?: so the
    // compiler emits v_cndmask chains (no scratch, no branches).
    float x0 = (i & 1) ? a.y : a.x;
    float x1 = (i & 1) ? a.w : a.z;
    float x2 = (i & 1) ? b.y : b.x;
    float x3 = (i & 1) ? b.w : b.z;
    float y0 = (i & 2) ? x1 : x0;
    float y1 = (i & 2) ? x3 : x2;
    return (i & 4) ? y1 : y0;
}

__global__ void Model_28681791602777_kernel(const float* __restrict__ vid,
                                            const int* __restrict__ lens,
                                            const int* __restrict__ ndt_ptr,
                                            float* __restrict__ out,
                                            int bs) {
    const int ndt = ndt_ptr[0];           // scalar broadcast (1-elem input)
    const int stride = gridDim.x * blockDim.x;
    int t = blockIdx.x * blockDim.x + threadIdx.x;

    if (ndt == 8) {                       // wave-uniform branch
        const int n2 = bs >> 1;           // pairs of rows
        const f32x4* vid4 = reinterpret_cast<const f32x4*>(vid);
        const i32x2* lens2 = reinterpret_cast<const i32x2*>(lens);
        f32x2* out2 = reinterpret_cast<f32x2*>(out);

        for (; t < n2; t += stride) {
            i32x2 l = lens2[t];
            const int vb = t << 2;        // 4 float4s per row pair
            f32x4 a0 = vid4[vb + 0];      // row 2t   lo
            f32x4 b0 = vid4[vb + 1];      // row 2t   hi
            f32x4 a1 = vid4[vb + 2];      // row 2t+1 lo
            f32x4 b1 = vid4[vb + 3];      // row 2t+1 hi
            f32x2 o;
            o.x = sel8(a0, b0, l.x - 1);
            o.y = sel8(a1, b1, l.y - 1);
            out2[t] = o;
        }
        // tail (bs odd) — first thread only
        if (blockIdx.x == 0 && threadIdx.x == 0) {
            for (int r = n2 << 1; r < bs; ++r)
                out[r] = vid[r * 8 + lens[r] - 1];
        }
    } else {
        // generic fallback: plain gather
        for (; t < bs; t += stride)
            out[t] = vid[t * ndt + lens[t] - 1];
    }
}

extern "C" void kernel_launch(void* const* d_in, const int* in_sizes, int n_in,
                              void* d_out, int out_size, void* d_ws, size_t ws_size,
                              hipStream_t stream) {
    const float* vid = (const float*)d_in[0];   // verified_id, BS*NDT f32
    const int* lens  = (const int*)d_in[1];     // accept_lens, BS i32
    const int* ndt   = (const int*)d_in[2];     // num_draft_tokens, 1 i32
    float* out = (float*)d_out;                 // BS f32

    const int bs = in_sizes[1];
    const int n2 = bs >> 1;

    const int block = 256;
    int grid = (n2 + block - 1) / block;
    if (grid > 8192) grid = 8192;               // grid-stride the rest
    if (grid < 1) grid = 1;

    Model_28681791602777_kernel<<<grid, block, 0, stream>>>(vid, lens, ndt, out, bs);
}